// Round 9
// baseline (718.361 us; speedup 1.0000x reference)
//
#include <hip/hip_runtime.h>
#include <math.h>

typedef __attribute__((ext_vector_type(8))) short bf16x8;   // 8 bf16 (4 VGPR) MFMA A/B frag
typedef __attribute__((ext_vector_type(4))) float f32x4;    // MFMA C/D frag

#define HH 256
#define WW 256
#define HW (HH*WW)
#define NORM_EPS 5e-5f

#define MFMA16(A,B,C) __builtin_amdgcn_mfma_f32_16x16x32_bf16((A),(B),(C),0,0,0)

// ws float offsets
#define OFF_RNORM   16384        // [n][k][j]
#define OFF_QBLK    540672       // [n][k][j][16]
#define OFF_VBLK    8929280      // [n][k][j][64]
// ws u16 offsets (weight region, bytes [0, 53248) = floats [0,13312) < 16384 OK)
#define WASMH_U 0                // [64 cout][64 ci] bf16 hi
#define WASML_U 4096             // lo
#define WMATH_U 8192             // [9 tap][16 cout][64 ci] bf16 hi
#define WMATL_U 17408            // lo

// ---------------------------------------------------------------- weight prep (fp32 -> split bf16)
__global__ void k_prep(const float* __restrict__ w_asm,
                       const float* __restrict__ w_match,
                       unsigned short* __restrict__ wsu) {
    int t = threadIdx.x;
    for (int i = t; i < 4096; i += 256) {          // w_asm [cout][ci]
        float v = w_asm[i];
        unsigned hh = __float_as_uint(v) & 0xFFFF0000u;
        float lo = v - __uint_as_float(hh);
        wsu[WASMH_U + i] = (unsigned short)(hh >> 16);
        wsu[WASML_U + i] = (unsigned short)(__float_as_uint(lo) >> 16);
    }
    for (int i = t; i < 9216; i += 256) {          // dest [tap][cout][ci]
        int tap = i >> 10, cout = (i >> 6) & 15, ci = i & 63;
        float v = w_match[(cout * 64 + ci) * 9 + tap];
        unsigned hh = __float_as_uint(v) & 0xFFFF0000u;
        float lo = v - __uint_as_float(hh);
        wsu[WMATH_U + i] = (unsigned short)(hh >> 16);
        wsu[WMATL_U + i] = (unsigned short)(__float_as_uint(lo) >> 16);
    }
}

// ---------------------------------------------------------------- fused MFMA convs -> Qblk, rnorm, Vblk
// block = (n, h, wseg): stages x rows h-1..h+1, w [ws0-1, ws0+64] as split-bf16
// LDS [row][wslot 0..65][ci 0..63] hi/lo planes, ci-stride 144 B.
__global__ __launch_bounds__(256, 2) void k_convs(const float* __restrict__ x,
                                                  const float* __restrict__ b_match,
                                                  const float* __restrict__ b_asm,
                                                  const unsigned short* __restrict__ wsu,
                                                  float* __restrict__ qblk,
                                                  float* __restrict__ rnorm,
                                                  float* __restrict__ vblk) {
    __shared__ __align__(16) unsigned char smx[57024];
    const int XL = 28512;
    const int b = blockIdx.x;
    const int n = b >> 10, h = (b >> 2) & 255, wseg = b & 3;
    const int ws0 = wseg * 64;
    const int t = threadIdx.x;
    const int wl = t & 63, cq = t >> 6;

    const float* xb = x + (size_t)n * 64 * HW;

    // ---- stage main region (lanes = w, coalesced)
    for (int r = 0; r < 3; ++r) {
        int hr = h - 1 + r;
        bool okh = (hr >= 0) && (hr < 256);
        unsigned hh[8], ll[8];
#pragma unroll
        for (int i2 = 0; i2 < 8; ++i2) {
            float v0 = 0.f, v1 = 0.f;
            if (okh) {
                int ci0 = cq * 16 + i2 * 2;
                v0 = xb[(size_t)ci0 * HW + hr * 256 + ws0 + wl];
                v1 = xb[(size_t)(ci0 + 1) * HW + hr * 256 + ws0 + wl];
            }
            unsigned u0 = __float_as_uint(v0) & 0xFFFF0000u;
            unsigned u1 = __float_as_uint(v1) & 0xFFFF0000u;
            float r0 = v0 - __uint_as_float(u0);
            float r1 = v1 - __uint_as_float(u1);
            hh[i2] = (u0 >> 16) | u1;
            ll[i2] = ((__float_as_uint(r0) & 0xFFFF0000u) >> 16) | (__float_as_uint(r1) & 0xFFFF0000u);
        }
        int base = (r * 66 + wl + 1) * 144 + cq * 32;
        *reinterpret_cast<uint4*>(smx + base)           = make_uint4(hh[0], hh[1], hh[2], hh[3]);
        *reinterpret_cast<uint4*>(smx + base + 16)      = make_uint4(hh[4], hh[5], hh[6], hh[7]);
        *reinterpret_cast<uint4*>(smx + XL + base)      = make_uint4(ll[0], ll[1], ll[2], ll[3]);
        *reinterpret_cast<uint4*>(smx + XL + base + 16) = make_uint4(ll[4], ll[5], ll[6], ll[7]);
    }
    // ---- halo columns (slots 0 and 65)
    if (t < 192) {
        int r = t >> 6, ci = t & 63;
        int hr = h - 1 + r;
        bool okh = (hr >= 0) && (hr < 256);
        float e0 = 0.f, e1 = 0.f;
        if (okh && ws0 > 0)   e0 = xb[(size_t)ci * HW + hr * 256 + ws0 - 1];
        if (okh && ws0 < 192) e1 = xb[(size_t)ci * HW + hr * 256 + ws0 + 64];
        unsigned u0 = __float_as_uint(e0) & 0xFFFF0000u;
        float l0 = e0 - __uint_as_float(u0);
        unsigned u1 = __float_as_uint(e1) & 0xFFFF0000u;
        float l1 = e1 - __uint_as_float(u1);
        *reinterpret_cast<unsigned short*>(smx + (r * 66 + 0) * 144 + ci * 2)       = (unsigned short)(u0 >> 16);
        *reinterpret_cast<unsigned short*>(smx + XL + (r * 66 + 0) * 144 + ci * 2)  = (unsigned short)(__float_as_uint(l0) >> 16);
        *reinterpret_cast<unsigned short*>(smx + (r * 66 + 65) * 144 + ci * 2)      = (unsigned short)(u1 >> 16);
        *reinterpret_cast<unsigned short*>(smx + XL + (r * 66 + 65) * 144 + ci * 2) = (unsigned short)(__float_as_uint(l1) >> 16);
    }
    __syncthreads();

    // ---- compute: wave wv owns 16-pixel M-tile
    const int lane = t & 63;
    const int wv = t >> 6;
    const int g = lane >> 4, l15 = lane & 15;

    f32x4 accV[4], accQ;
    {
        float bq = b_match[l15];
        accQ = (f32x4){bq, bq, bq, bq};
#pragma unroll
        for (int nt = 0; nt < 4; ++nt) {
            float bv = b_asm[nt * 16 + l15];
            accV[nt] = (f32x4){bv, bv, bv, bv};
        }
    }

    // conv1x1: row 1, center slot
    {
        int ab = (66 + wv * 16 + l15 + 1) * 144 + g * 16;
        bf16x8 Ah0 = *reinterpret_cast<const bf16x8*>(smx + ab);
        bf16x8 Ah1 = *reinterpret_cast<const bf16x8*>(smx + ab + 64);
        bf16x8 Al0 = *reinterpret_cast<const bf16x8*>(smx + XL + ab);
        bf16x8 Al1 = *reinterpret_cast<const bf16x8*>(smx + XL + ab + 64);
#pragma unroll
        for (int nt = 0; nt < 4; ++nt) {
            const unsigned short* bp = wsu + (nt * 16 + l15) * 64 + g * 8;
            bf16x8 Bh0 = *reinterpret_cast<const bf16x8*>(bp + WASMH_U);
            bf16x8 Bh1 = *reinterpret_cast<const bf16x8*>(bp + WASMH_U + 32);
            bf16x8 Bl0 = *reinterpret_cast<const bf16x8*>(bp + WASML_U);
            bf16x8 Bl1 = *reinterpret_cast<const bf16x8*>(bp + WASML_U + 32);
            accV[nt] = MFMA16(Ah0, Bh0, accV[nt]);
            accV[nt] = MFMA16(Ah1, Bh1, accV[nt]);
            accV[nt] = MFMA16(Al0, Bh0, accV[nt]);
            accV[nt] = MFMA16(Al1, Bh1, accV[nt]);
            accV[nt] = MFMA16(Ah0, Bl0, accV[nt]);
            accV[nt] = MFMA16(Ah1, Bl1, accV[nt]);
        }
    }
    // conv3x3: 9 taps
#pragma unroll
    for (int dy = 0; dy < 3; ++dy) {
#pragma unroll
        for (int dx = 0; dx < 3; ++dx) {
            int tap = dy * 3 + dx;
            int ab = (dy * 66 + wv * 16 + l15 + dx) * 144 + g * 16;
            bf16x8 Ah0 = *reinterpret_cast<const bf16x8*>(smx + ab);
            bf16x8 Ah1 = *reinterpret_cast<const bf16x8*>(smx + ab + 64);
            bf16x8 Al0 = *reinterpret_cast<const bf16x8*>(smx + XL + ab);
            bf16x8 Al1 = *reinterpret_cast<const bf16x8*>(smx + XL + ab + 64);
            const unsigned short* bp = wsu + (tap * 16 + l15) * 64 + g * 8;
            bf16x8 Bh0 = *reinterpret_cast<const bf16x8*>(bp + WMATH_U);
            bf16x8 Bh1 = *reinterpret_cast<const bf16x8*>(bp + WMATH_U + 32);
            bf16x8 Bl0 = *reinterpret_cast<const bf16x8*>(bp + WMATL_U);
            bf16x8 Bl1 = *reinterpret_cast<const bf16x8*>(bp + WMATL_U + 32);
            accQ = MFMA16(Ah0, Bh0, accQ);
            accQ = MFMA16(Ah1, Bh1, accQ);
            accQ = MFMA16(Al0, Bh0, accQ);
            accQ = MFMA16(Al1, Bh1, accQ);
            accQ = MFMA16(Ah0, Bl0, accQ);
            accQ = MFMA16(Ah1, Bl1, accQ);
        }
    }

    // ---- epilogue: Q + rnorm + V (D layout: col=l15=cout, row=4g+r=pixel)
    const int khi = (h & 15) << 4;
    const int j = ((h >> 4) << 4) | (wseg * 4 + wv);
#pragma unroll
    for (int r = 0; r < 4; ++r) {
        float v = accQ[r];
        float ss = v * v;
        ss += __shfl_xor(ss, 1, 64);
        ss += __shfl_xor(ss, 2, 64);
        ss += __shfl_xor(ss, 4, 64);
        ss += __shfl_xor(ss, 8, 64);
        int m = 4 * g + r;
        size_t rowbase = ((size_t)(n * 256 + (khi | m))) * 256 + j;
        qblk[rowbase * 16 + l15] = v;
        if (l15 == 0) rnorm[rowbase] = 1.0f / fmaxf(sqrtf(ss), NORM_EPS);
    }
#pragma unroll
    for (int nt = 0; nt < 4; ++nt) {
#pragma unroll
        for (int r = 0; r < 4; ++r) {
            int m = 4 * g + r;
            size_t rowbase = ((size_t)(n * 256 + (khi | m))) * 256 + j;
            vblk[rowbase * 64 + nt * 16 + l15] = accV[nt][r];
        }
    }
}

// ---------------------------------------------------------------- MFMA attention per (n,k)  [unchanged, passing]
#define QP  0
#define KP  20480
#define VTH 40960
#define VTL 50176
#define PB  59392

__global__ __launch_bounds__(256, 2) void k_attn(const float* __restrict__ ws_r,
                                                 float* __restrict__ vblk) {
    __shared__ __align__(16) unsigned char sm[64512];
    const int tid  = threadIdx.x;
    const int lane = tid & 63;
    const int wv   = tid >> 6;
    const int g    = lane >> 4;
    const int l15  = lane & 15;
    const bool hi32 = lane >= 32;
    const int b = blockIdx.x;

    const bf16x8 zfrag = {0,0,0,0,0,0,0,0};

    const float* qbase  = ws_r + OFF_QBLK  + (size_t)b * (256 * 16);
    const float* rnbase = ws_r + OFF_RNORM + (size_t)b * 256;
    float* vbase = vblk + (size_t)b * (256 * 64);

    // ---- stage Q/K into LDS as split bf16 (rn folded into K)
    {
        const int t = tid;                     // row j
        float rn = rnbase[t];
        const float4* q4 = reinterpret_cast<const float4*>(qbase + t * 16);
        float q[16];
#pragma unroll
        for (int r = 0; r < 4; ++r) {
            float4 v = q4[r];
            q[4*r+0] = v.x; q[4*r+1] = v.y; q[4*r+2] = v.z; q[4*r+3] = v.w;
        }
        unsigned qh[8], ql[8], kh[8], kl[8];
#pragma unroll
        for (int e = 0; e < 8; ++e) {
            float a0 = q[2*e], a1 = q[2*e+1];
            unsigned u0 = __float_as_uint(a0) & 0xFFFF0000u;
            unsigned u1 = __float_as_uint(a1) & 0xFFFF0000u;
            float r0 = a0 - __uint_as_float(u0);
            float r1 = a1 - __uint_as_float(u1);
            qh[e] = (u0 >> 16) | u1;
            ql[e] = ((__float_as_uint(r0) & 0xFFFF0000u) >> 16) | (__float_as_uint(r1) & 0xFFFF0000u);
            float k0 = a0 * rn, k1 = a1 * rn;
            unsigned v0 = __float_as_uint(k0) & 0xFFFF0000u;
            unsigned v1 = __float_as_uint(k1) & 0xFFFF0000u;
            float s0 = k0 - __uint_as_float(v0);
            float s1 = k1 - __uint_as_float(v1);
            kh[e] = (v0 >> 16) | v1;
            kl[e] = ((__float_as_uint(s0) & 0xFFFF0000u) >> 16) | (__float_as_uint(s1) & 0xFFFF0000u);
        }
        uint4* qrow = reinterpret_cast<uint4*>(sm + QP + t * 80);
        qrow[0] = make_uint4(qh[0], qh[1], qh[2], qh[3]);
        qrow[1] = make_uint4(qh[4], qh[5], qh[6], qh[7]);
        qrow[2] = make_uint4(ql[0], ql[1], ql[2], ql[3]);
        qrow[3] = make_uint4(ql[4], ql[5], ql[6], ql[7]);
        uint4* krow = reinterpret_cast<uint4*>(sm + KP + t * 80);
        krow[0] = make_uint4(kh[0], kh[1], kh[2], kh[3]);
        krow[1] = make_uint4(kh[4], kh[5], kh[6], kh[7]);
        krow[2] = make_uint4(kl[0], kl[1], kl[2], kl[3]);
        krow[3] = make_uint4(kl[4], kl[5], kl[6], kl[7]);
    }
    __syncthreads();

    // ---- hold Q B-operand frags in registers for the whole kernel
    bf16x8 qb1[4], qb2[4];
#pragma unroll
    for (int it = 0; it < 4; ++it) {
        int i0 = wv * 64 + it * 16;
        qb1[it] = *reinterpret_cast<const bf16x8*>(sm + QP + (i0 + l15) * 80 + (g & 1) * 16);
        bf16x8 t2 = *reinterpret_cast<const bf16x8*>(sm + QP + (i0 + l15) * 80 + 32 + (g & 1) * 16);
        qb2[it] = hi32 ? zfrag : t2;           // [ql | 0]
    }

    // ---- pass 1: row max (over j) per output row i  (lane's col = l15)
    float mrow[4] = {-1e30f, -1e30f, -1e30f, -1e30f};
    for (int jt = 0; jt < 16; ++jt) {
        bf16x8 kf = *reinterpret_cast<const bf16x8*>(sm + KP + (jt * 16 + l15) * 80 + g * 16);
#pragma unroll
        for (int it = 0; it < 4; ++it) {
            f32x4 s = {0.f, 0.f, 0.f, 0.f};
            s = MFMA16(kf, qb1[it], s);
            s = MFMA16(kf, qb2[it], s);
            bool dtile = (jt * 16 == wv * 64 + it * 16);
#pragma unroll
            for (int r = 0; r < 4; ++r) {
                float v = s[r];
                if (dtile && (4 * g + r == l15)) v = -1e30f;
                mrow[it] = fmaxf(mrow[it], v);
            }
        }
    }
#pragma unroll
    for (int it = 0; it < 4; ++it) {
        float m = mrow[it];
        m = fmaxf(m, __shfl_xor(m, 16, 64));
        m = fmaxf(m, __shfl_xor(m, 32, 64));
        mrow[it] = m;
    }

    // ---- pass 2: P = exp(S-m) split bf16 -> O^T accum
    float lsum[4] = {0.f, 0.f, 0.f, 0.f};
    f32x4 acc[4][4];
#pragma unroll
    for (int it = 0; it < 4; ++it)
#pragma unroll
        for (int ct = 0; ct < 4; ++ct) acc[it][ct] = (f32x4){0.f, 0.f, 0.f, 0.f};

    for (int ch = 0; ch < 4; ++ch) {
        __syncthreads();                       // previous chunk's Vt fully consumed
        {   // stage V chunk: 64 j x 64 c, split hi/lo, transposed [c][j]
            int c = tid >> 2, jq = tid & 3;
            const float* vg = vbase + (size_t)(ch * 64) * 64 + c;
#pragma unroll
            for (int s2 = 0; s2 < 8; ++s2) {
                int jl = jq * 16 + s2 * 2;
                float v0 = vg[(size_t)jl * 64];
                float v1 = vg[(size_t)(jl + 1) * 64];
                unsigned u0 = __float_as_uint(v0) & 0xFFFF0000u;
                unsigned u1 = __float_as_uint(v1) & 0xFFFF0000u;
                float r0 = v0 - __uint_as_float(u0);
                float r1 = v1 - __uint_as_float(u1);
                *reinterpret_cast<unsigned*>(sm + VTH + c * 144 + jl * 2) = (u0 >> 16) | u1;
                *reinterpret_cast<unsigned*>(sm + VTL + c * 144 + jl * 2) =
                    ((__float_as_uint(r0) & 0xFFFF0000u) >> 16) | (__float_as_uint(r1) & 0xFFFF0000u);
            }
        }
        __syncthreads();

#pragma unroll
        for (int jt = 0; jt < 4; ++jt) {
            int jg0 = ch * 64 + jt * 16;
            int jl0 = jt * 16;
            bf16x8 kf = *reinterpret_cast<const bf16x8*>(sm + KP + (jg0 + l15) * 80 + g * 16);
            bf16x8 vh[4], vl[4];
#pragma unroll
            for (int ct = 0; ct < 4; ++ct) {
                vh[ct] = *reinterpret_cast<const bf16x8*>(
                    sm + VTH + (ct * 16 + l15) * 144 + (jl0 + 8 * (g & 1)) * 2);
                bf16x8 t2 = *reinterpret_cast<const bf16x8*>(
                    sm + VTL + (ct * 16 + l15) * 144 + (jl0 + 8 * (g & 1)) * 2);
                vl[ct] = hi32 ? zfrag : t2;    // [Vl | 0]
            }
#pragma unroll
            for (int it = 0; it < 4; ++it) {
                f32x4 s = {0.f, 0.f, 0.f, 0.f};
                s = MFMA16(kf, qb1[it], s);
                s = MFMA16(kf, qb2[it], s);
                bool dtile = (jg0 == wv * 64 + it * 16);
                unsigned pd[4];
#pragma unroll
                for (int r = 0; r < 4; ++r) {
                    float p = __expf(s[r] - mrow[it]);
                    if (dtile && (4 * g + r == l15)) p = 0.f;
                    lsum[it] += p;
                    unsigned uh = __float_as_uint(p) & 0xFFFF0000u;
                    float lo = p - __uint_as_float(uh);
                    unsigned ul = __float_as_uint(lo) & 0xFFFF0000u;
                    pd[r] = (uh >> 16) | ul;   // lo16 = Ph, hi16 = Pl
                }
                // stage P tile (wave-private, no barrier)
                *reinterpret_cast<uint4*>(sm + PB + wv * 1280 + l15 * 80 + g * 16) =
                    make_uint4(pd[0], pd[1], pd[2], pd[3]);
                const uint4 d0 = *reinterpret_cast<const uint4*>(sm + PB + wv * 1280 + l15 * 80 + (g & 1) * 32);
                const uint4 d1 = *reinterpret_cast<const uint4*>(sm + PB + wv * 1280 + l15 * 80 + (g & 1) * 32 + 16);
                unsigned bw0, bw1, bw2, bw3;
                if (!hi32) {                   // Ph halves
                    bw0 = (d0.x & 0xFFFFu) | (d0.y << 16);
                    bw1 = (d0.z & 0xFFFFu) | (d0.w << 16);
                    bw2 = (d1.x & 0xFFFFu) | (d1.y << 16);
                    bw3 = (d1.z & 0xFFFFu) | (d1.w << 16);
                } else {                       // Pl halves
                    bw0 = (d0.x >> 16) | (d0.y & 0xFFFF0000u);
                    bw1 = (d0.z >> 16) | (d0.w & 0xFFFF0000u);
                    bw2 = (d1.x >> 16) | (d1.y & 0xFFFF0000u);
                    bw3 = (d1.z >> 16) | (d1.w & 0xFFFF0000u);
                }
                union { uint4 u; bf16x8 s8; } pb_u;
                pb_u.u = make_uint4(bw0, bw1, bw2, bw3);
                bf16x8 pb = pb_u.s8;
#pragma unroll
                for (int ct = 0; ct < 4; ++ct) {
                    acc[it][ct] = MFMA16(vh[ct], pb, acc[it][ct]);
                    acc[it][ct] = MFMA16(vl[ct], pb, acc[it][ct]);
                }
            }
        }
    }

    // ---- finalize: l reduce, transpose O^T -> O rows via LDS, coalesced store
#pragma unroll
    for (int it = 0; it < 4; ++it) {
        float l = lsum[it];
        l += __shfl_xor(l, 16, 64);
        l += __shfl_xor(l, 32, 64);
        lsum[it] = 1.0f / l;
    }

    __syncthreads();                           // Vt region now reusable
    const int obase = VTH + wv * 4352;         // per-wave [16][68] f32
#pragma unroll
    for (int it = 0; it < 4; ++it) {
#pragma unroll
        for (int ct = 0; ct < 4; ++ct) {
#pragma unroll
            for (int r = 0; r < 4; ++r) {
                int c = ct * 16 + 4 * g + r;
                *reinterpret_cast<float*>(sm + obase + l15 * 272 + c * 4) =
                    acc[it][ct][r] * lsum[it];
            }
        }
        int ir = lane >> 2, cq = lane & 3;
        float* orow = vbase + (size_t)(wv * 64 + it * 16 + ir) * 64 + cq * 16;
#pragma unroll
        for (int k4 = 0; k4 < 4; ++k4) {
            float4 ov = *reinterpret_cast<const float4*>(sm + obase + ir * 272 + cq * 64 + k4 * 16);
            reinterpret_cast<float4*>(orow)[k4] = ov;
        }
    }
}

// ---------------------------------------------------------------- unblockify + residual
__global__ __launch_bounds__(256) void k_unblock(const float* __restrict__ oblk,
                                                 const float* __restrict__ x,
                                                 float* __restrict__ out) {
    int b = blockIdx.x;
    int n = b >> 8, h = b & 255;
    int t = threadIdx.x;
    int c = t & 63, wq = t >> 6;
    int kh = h & 15, jh = h >> 4;

    const float* ob = oblk + ((size_t)n << 22);
    size_t xoff = (((size_t)(n * 64 + c)) << 16) + ((size_t)h << 8);
    const float4* xr   = reinterpret_cast<const float4*>(x + xoff);
    float4*       outr = reinterpret_cast<float4*>(out + xoff);

    for (int it = 0; it < 16; ++it) {
        int w4 = wq * 16 + it;
        int w0 = w4 * 4;
        float vals[4];
#pragma unroll
        for (int r = 0; r < 4; ++r) {
            int w = w0 + r;
            int wm = w & 15, wd = w >> 4;
            vals[r] = ob[(((size_t)(kh * 16 + wm)) << 14) + ((jh * 16 + wd) << 6) + c];
        }
        float4 xv = xr[w4];
        outr[w4] = make_float4(vals[0] + xv.x, vals[1] + xv.y, vals[2] + xv.z, vals[3] + xv.w);
    }
}

// ---------------------------------------------------------------- launch
extern "C" void kernel_launch(void* const* d_in, const int* in_sizes, int n_in,
                              void* d_out, int out_size, void* d_ws, size_t ws_size,
                              hipStream_t stream) {
    const float* x       = (const float*)d_in[0];
    const float* w_match = (const float*)d_in[1];
    const float* b_match = (const float*)d_in[2];
    const float* w_asm   = (const float*)d_in[3];
    const float* b_asm   = (const float*)d_in[4];
    float* out = (float*)d_out;
    float* ws  = (float*)d_ws;

    k_prep<<<1, 256, 0, stream>>>(w_asm, w_match, (unsigned short*)d_ws);
    k_convs<<<8192, 256, 0, stream>>>(x, b_match, b_asm, (const unsigned short*)d_ws,
                                      ws + OFF_QBLK, ws + OFF_RNORM, ws + OFF_VBLK);
    k_attn<<<2048, 256, 0, stream>>>(ws, ws + OFF_VBLK);
    k_unblock<<<2048, 256, 0, stream>>>(ws + OFF_VBLK, x, out);
}